// Round 6
// baseline (366.695 us; speedup 1.0000x reference)
//
#include <hip/hip_runtime.h>
#include <hip/hip_bf16.h>

#define NB 256
#define NN 1024
#define NSTAGES 11
#define EPSF 1e-7f

typedef unsigned short u16;
typedef unsigned int u32;
typedef unsigned long long u64;
typedef __attribute__((ext_vector_type(8))) short short8;
typedef __attribute__((ext_vector_type(16))) float f32x16;

// Output layout (float32, concatenated):
//   losses (B, 11, N); preds (B, N, 11, 2); norms (B, 11, N)
static constexpr size_t PRED_BASE = (size_t)NB * NSTAGES * NN;
static constexpr size_t NORM_BASE = PRED_BASE + (size_t)NB * NN * NSTAGES * 2;

// wfrag (u16 units): 48 B-fragments for mfma_f32_32x32x16_bf16, channel-pair
// permuted: B[k][n] at lane l, frag (ks,nt): n = 2*(l&31)+nt, k = ks*16+(l>>5)*8+j.
//   cn_W1: 0..15 (K=128) | bn_W1[0:128]: 16..31 | cn_W2: 32..39 | bn_W2: 40..47
//   packed llr_W bf16 pairs (u32[64]) at u16 offset 24576
// labW_g (separate fp32[2][64]): lab_emb[v] @ bn_W1[128:192] + bn_b1  (prep-fused)
static constexpr int LW_OFF = 24576;

__device__ __forceinline__ u16 f2bf(float f) {
  unsigned u = __float_as_uint(f);
  unsigned r = (u + 0x7fffu + ((u >> 16) & 1u)) >> 16;
  return (u16)r;
}
__device__ __forceinline__ unsigned pack_bf2(float a, float b) {
  __hip_bfloat162 h = __float22bfloat162_rn(make_float2(a, b));
  return *(unsigned*)&h;
}
__device__ __forceinline__ u32 spread16(u32 v) {
  v = (v | (v << 8)) & 0x00FF00FFu;
  v = (v | (v << 4)) & 0x0F0F0F0Fu;
  v = (v | (v << 2)) & 0x33333333u;
  v = (v | (v << 1)) & 0x55555555u;
  return v;
}

// losses+norms -> out (harness layout is burst-friendly there);
// preds -> staging buffer psta in coalesced (b, s, n, 2) layout.
__device__ __forceinline__ void emit_lnp(float* __restrict__ out, float* __restrict__ psta,
                                         int b, int n, int s,
                                         float z0, float z1, float nrm2, int label) {
  float m  = fmaxf(z0, z1);
  float p0 = expf(z0 - m), p1 = expf(z1 - m);
  float inv = 1.0f / (p0 + p1);
  p0 *= inv; p1 *= inv;
  float pt = label ? p1 : p0;
  pt = fminf(fmaxf(pt, EPSF), 1.0f);
  out[((size_t)b * NSTAGES + s) * NN + n] = -logf(pt);
  *(float2*)(psta + ((size_t)b * NSTAGES + s) * (NN * 2) + 2 * n) = make_float2(p0, p1);
  out[NORM_BASE + ((size_t)b * NSTAGES + s) * NN + n] = sqrtf(nrm2);
}

// Swizzled e-LDS addressing (u16 units). Row = 64 u16 (128 B) = 8 chunks of
// 16 B; physical chunk = logical_chunk XOR (row & 7).
__device__ __forceinline__ int eaddr(int row, int c16) {
  return row * 64 + (((c16) ^ (row & 7)) << 3);
}
__device__ __forceinline__ int eaddr32(int row, int m31) {
  return row * 64 + (((((m31) >> 2) ^ (row & 7)) << 3) | (((m31) & 3) << 1));
}

__global__ __launch_bounds__(256) void prep_kernel(
    const float* __restrict__ cn_W1, const float* __restrict__ bn_W1,
    const float* __restrict__ cn_W2, const float* __restrict__ bn_W2,
    const float* __restrict__ lab_emb, const float* __restrict__ llr_W,
    const float* __restrict__ bn_b1,
    u16* __restrict__ wfrag, float* __restrict__ labW_g) {
  int t = blockIdx.x * 256 + threadIdx.x;
  if (t < 3072) {
    int f = t >> 6, l = t & 63, h = l >> 5, c = l & 31;
    const float* src; int ks, nt;
    if (f < 16)      { src = cn_W1; ks = f >> 1; nt = f & 1; }
    else if (f < 32) { int g = f - 16; src = bn_W1; ks = g >> 1; nt = g & 1; }
    else if (f < 40) { int g = f - 32; src = cn_W2; ks = g >> 1; nt = g & 1; }
    else             { int g = f - 40; src = bn_W2; ks = g >> 1; nt = g & 1; }
    int col = 2 * c + nt;
    u16 vals[8];
    #pragma unroll
    for (int j = 0; j < 8; ++j) {
      int k = ks * 16 + h * 8 + j;
      vals[j] = f2bf(src[k * 64 + col]);
    }
    uint4 u;
    u.x = (unsigned)vals[0] | ((unsigned)vals[1] << 16);
    u.y = (unsigned)vals[2] | ((unsigned)vals[3] << 16);
    u.z = (unsigned)vals[4] | ((unsigned)vals[5] << 16);
    u.w = (unsigned)vals[6] | ((unsigned)vals[7] << 16);
    *(uint4*)(wfrag + (size_t)t * 8) = u;
  } else if (t < 3136) {
    int k = t - 3072;
    unsigned wv = (unsigned)f2bf(llr_W[k * 2]) | ((unsigned)f2bf(llr_W[k * 2 + 1]) << 16);
    ((unsigned*)(wfrag + LW_OFF))[k] = wv;
  } else if (t < 3264) {
    int idx = t - 3136;
    int v = idx >> 6, c = idx & 63;
    float acc = bn_b1[c];
    for (int d = 0; d < 64; ++d)
      acc = fmaf(lab_emb[v * 64 + d], bn_W1[(128 + d) * 64 + c], acc);
    labW_g[idx] = acc;
  }
}

#define BFR(FI) (((FI) < 28) ? *(const short8*)(wlds + (FI) * 512 + ln * 8) \
                             : *(const short8*)(wfrag + (FI) * 512 + ln * 8))

// Persistent kernel: 1 block per batch row b, e-row (1024x64 bf16 = 128 KB)
// resident in LDS across all 10 stages. 512 threads = 8 waves; wave w owns
// pairs [64w, 64w+64) as 2 tiles of 32 (mfma_f32_32x32x16_bf16).
__global__ __launch_bounds__(512) void polar_kernel(
    const int* __restrict__ x, const float* __restrict__ y,
    const float* __restrict__ emb_W, const float* __restrict__ emb_b,
    const u16* __restrict__ wfrag, const float* __restrict__ labW_g,
    const float* __restrict__ cn_b1, const float* __restrict__ cn_b2,
    const float* __restrict__ bn_b2, const float* __restrict__ llr_W,
    const float* __restrict__ llr_b, float* __restrict__ out,
    float* __restrict__ psta) {
  __shared__ __align__(16) u16 eL[NN * 64];        // 131072 B
  __shared__ __align__(16) u16 wlds[28 * 512];     // 28672 B
  __shared__ u32 vmask[2][32];
  __shared__ float labW[2][64];

  const int tid = threadIdx.x;
  const int w = tid >> 6, ln = tid & 63;
  const int m31 = ln & 31, h8 = ln >> 5;
  const int b = blockIdx.x;

  for (int i = tid; i < 28 * 64; i += 512)
    ((uint4*)wlds)[i] = ((const uint4*)wfrag)[i];
  if (tid < 128) ((float*)labW)[tid] = labW_g[tid];

  const float lb0 = llr_b[0], lb1 = llr_b[1];
  const float2 cb1 = *(const float2*)(cn_b1 + 2 * m31);
  const float2 cb2 = *(const float2*)(cn_b2 + 2 * m31);
  const float2 bb2 = *(const float2*)(bn_b2 + 2 * m31);

  // ---------------- stage 0: e = y @ emb_W + emb_b ----------------
  #pragma unroll
  for (int rep = 0; rep < 2; ++rep) {
    int n = rep * 512 + tid;
    float2 yv = *(const float2*)(y + ((size_t)b * NN + n) * 2);
    float z0 = lb0, z1 = lb1, nr = 0.f;
    #pragma unroll
    for (int o8 = 0; o8 < 8; ++o8) {
      u32 vals[4];
      #pragma unroll
      for (int jj = 0; jj < 4; ++jj) {
        int o = o8 * 8 + jj * 2;
        float e0 = fmaf(yv.x, emb_W[o],     fmaf(yv.y, emb_W[64 + o],     emb_b[o]));
        float e1 = fmaf(yv.x, emb_W[o + 1], fmaf(yv.y, emb_W[64 + o + 1], emb_b[o + 1]));
        vals[jj] = pack_bf2(e0, e1);
        z0 = fmaf(e0, llr_W[o * 2 + 0], z0); z1 = fmaf(e0, llr_W[o * 2 + 1], z1);
        nr = fmaf(e0, e0, nr);
        z0 = fmaf(e1, llr_W[o * 2 + 2], z0); z1 = fmaf(e1, llr_W[o * 2 + 3], z1);
        nr = fmaf(e1, e1, nr);
      }
      uint4 q; q.x = vals[0]; q.y = vals[1]; q.z = vals[2]; q.w = vals[3];
      *(uint4*)(eL + eaddr(n, o8)) = q;
    }
    int v = x[(size_t)b * NN + n] & 1;
    emit_lnp(out, psta, b, n, 0, z0, z1, nr, v);
    u64 bm = __ballot(v != 0);
    if (ln == 0)  vmask[0][rep * 16 + 2 * w]     = (u32)bm;
    if (ln == 32) vmask[0][rep * 16 + 2 * w + 1] = (u32)(bm >> 32);
  }
  __syncthreads();

  const float2 lwv0 = *(const float2*)(&labW[0][2 * m31]);
  const float2 lwv1 = *(const float2*)(&labW[1][2 * m31]);

  // ---------------- stages 1..10 ----------------
  #pragma unroll 1
  for (int s = 1; s <= 10; ++s) {
    const int sh = s - 1;
    const int half = 1 << sh;
    const u32* vmR = vmask[(s - 1) & 1];
    u32* vmW = vmask[s & 1];

    short8 Ao[2][4], Ae[2][4];
    int io[2], ie[2], vo[2], ve[2], vx[2];
    u32 bxs[2];
    #pragma unroll
    for (int t = 0; t < 2; ++t) {
      int i = 64 * w + 32 * t + m31;
      int g = i >> sh, u = i & (half - 1);
      io[t] = g * (half << 1) + u;
      ie[t] = io[t] + half;
      #pragma unroll
      for (int f = 0; f < 4; ++f) {
        Ao[t][f] = *(const short8*)(eL + eaddr(io[t], f * 2 + h8));
        Ae[t][f] = *(const short8*)(eL + eaddr(ie[t], f * 2 + h8));
      }
      vo[t] = (vmR[io[t] >> 5] >> (io[t] & 31)) & 1;
      ve[t] = (vmR[ie[t] >> 5] >> (ie[t] & 31)) & 1;
      vx[t] = vo[t] ^ ve[t];
      u32 bx = (u32)__ballot(vx[t] != 0);
      u32 be = (u32)__ballot(ve[t] != 0);
      bxs[t] = bx;
      u32 lo = spread16(bx & 0xffffu) | (spread16(be & 0xffffu) << 1);
      u32 hi = spread16(bx >> 16) | (spread16(be >> 16) << 1);
      if (ln == 0) { vmW[4 * w + 2 * t] = lo; vmW[4 * w + 2 * t + 1] = hi; }
    }
    __syncthreads();   // all e reads done; output rows now writable

    // piggybacked loss/pred/norm for stage s-1; all 64 lanes emit (side = h8)
    if (s >= 2) {
      const uint4* lwq = (const uint4*)(wfrag + LW_OFF);
      uint4 lq[4][2];
      #pragma unroll
      for (int f = 0; f < 4; ++f) {
        lq[f][0] = lwq[f * 4 + h8 * 2];
        lq[f][1] = lwq[f * 4 + h8 * 2 + 1];
      }
      #pragma unroll
      for (int t = 0; t < 2; ++t) {
        float zz[2][3];
        #pragma unroll
        for (int side = 0; side < 2; ++side) {
          float z0 = 0.f, z1 = 0.f, nr = 0.f;
          #pragma unroll
          for (int f = 0; f < 4; ++f) {
            short8 av8 = side ? Ae[t][f] : Ao[t][f];
            #pragma unroll
            for (int j = 0; j < 8; ++j) {
              u32 pv = ((const u32*)&av8)[j >> 1];
              float val = __uint_as_float((j & 1) ? (pv & 0xffff0000u) : (pv << 16));
              u32 lwp = (j < 4) ? ((const u32*)&lq[f][0])[j] : ((const u32*)&lq[f][1])[j - 4];
              z0 = fmaf(val, __uint_as_float(lwp << 16), z0);
              z1 = fmaf(val, __uint_as_float(lwp & 0xffff0000u), z1);
              nr = fmaf(val, val, nr);
            }
          }
          zz[side][0] = z0 + __shfl_xor(z0, 32);
          zz[side][1] = z1 + __shfl_xor(z1, 32);
          zz[side][2] = nr + __shfl_xor(nr, 32);
        }
        int n    = h8 ? ie[t] : io[t];
        int lab  = h8 ? ve[t] : vo[t];
        emit_lnp(out, psta, b, n, s - 1,
                 zz[h8][0] + lb0, zz[h8][1] + lb1, zz[h8][2], lab);
      }
    }

    // ---- layer-1 cn (K=128) -> H_cn dense at rows [128w+64t, +32) ----
    f32x16 a0[2], a1[2];
    #pragma unroll
    for (int t = 0; t < 2; ++t)
      #pragma unroll
      for (int r = 0; r < 16; ++r) { a0[t][r] = cb1.x; a1[t][r] = cb1.y; }
    #pragma unroll
    for (int ks = 0; ks < 8; ++ks) {
      short8 B0 = BFR(ks * 2 + 0);
      short8 B1 = BFR(ks * 2 + 1);
      #pragma unroll
      for (int t = 0; t < 2; ++t) {
        short8 a = (ks < 4) ? Ao[t][ks] : Ae[t][ks - 4];
        a0[t] = __builtin_amdgcn_mfma_f32_32x32x16_bf16(a, B0, a0[t], 0, 0, 0);
        a1[t] = __builtin_amdgcn_mfma_f32_32x32x16_bf16(a, B1, a1[t], 0, 0, 0);
      }
    }
    #pragma unroll
    for (int t = 0; t < 2; ++t) {
      int hbase = 128 * w + 64 * t;
      #pragma unroll
      for (int r = 0; r < 16; ++r) {
        int row = (r & 3) + 8 * (r >> 2) + 4 * h8;
        *(u32*)(eL + eaddr32(hbase + row, m31)) =
            pack_bf2(fmaxf(a0[t][r], 0.f), fmaxf(a1[t][r], 0.f));
      }
    }

    // ---- layer-1 bn (K=128 + fused labW bias) -> H_bn at rows [+32, +64) ----
    #pragma unroll
    for (int t = 0; t < 2; ++t)
      #pragma unroll
      for (int r = 0; r < 16; ++r) {
        int row = (r & 3) + 8 * (r >> 2) + 4 * h8;
        int bit = (bxs[t] >> row) & 1;
        a0[t][r] = bit ? lwv1.x : lwv0.x;
        a1[t][r] = bit ? lwv1.y : lwv0.y;
      }
    #pragma unroll
    for (int ks = 0; ks < 8; ++ks) {
      short8 B0 = BFR(16 + ks * 2 + 0);
      short8 B1 = BFR(16 + ks * 2 + 1);
      #pragma unroll
      for (int t = 0; t < 2; ++t) {
        short8 a = (ks < 4) ? Ao[t][ks] : Ae[t][ks - 4];
        a0[t] = __builtin_amdgcn_mfma_f32_32x32x16_bf16(a, B0, a0[t], 0, 0, 0);
        a1[t] = __builtin_amdgcn_mfma_f32_32x32x16_bf16(a, B1, a1[t], 0, 0, 0);
      }
    }
    #pragma unroll
    for (int t = 0; t < 2; ++t) {
      int hbase = 128 * w + 64 * t + 32;
      #pragma unroll
      for (int r = 0; r < 16; ++r) {
        int row = (r & 3) + 8 * (r >> 2) + 4 * h8;
        *(u32*)(eL + eaddr32(hbase + row, m31)) =
            pack_bf2(fmaxf(a0[t][r], 0.f), fmaxf(a1[t][r], 0.f));
      }
    }

    // ---- layer-2 per tile: read H (dense rows), MFMA, write e' in place ----
    #pragma unroll
    for (int t = 0; t < 2; ++t) {
      int hbase = 128 * w + 64 * t;
      short8 Hc[4], Hb[4];
      #pragma unroll
      for (int f = 0; f < 4; ++f) {
        Hc[f] = *(const short8*)(eL + eaddr(hbase + m31, f * 2 + h8));
        Hb[f] = *(const short8*)(eL + eaddr(hbase + 32 + m31, f * 2 + h8));
      }
      f32x16 d0, d1, e0v, e1v;
      #pragma unroll
      for (int r = 0; r < 16; ++r) { d0[r] = cb2.x; d1[r] = cb2.y; e0v[r] = bb2.x; e1v[r] = bb2.y; }
      #pragma unroll
      for (int ks = 0; ks < 4; ++ks) {
        short8 B0 = BFR(32 + ks * 2 + 0);
        short8 B1 = BFR(32 + ks * 2 + 1);
        short8 C0 = BFR(40 + ks * 2 + 0);
        short8 C1 = BFR(40 + ks * 2 + 1);
        d0  = __builtin_amdgcn_mfma_f32_32x32x16_bf16(Hc[ks], B0, d0, 0, 0, 0);
        d1  = __builtin_amdgcn_mfma_f32_32x32x16_bf16(Hc[ks], B1, d1, 0, 0, 0);
        e0v = __builtin_amdgcn_mfma_f32_32x32x16_bf16(Hb[ks], C0, e0v, 0, 0, 0);
        e1v = __builtin_amdgcn_mfma_f32_32x32x16_bf16(Hb[ks], C1, e1v, 0, 0, 0);
      }
      #pragma unroll
      for (int r = 0; r < 16; ++r) {
        int row = (r & 3) + 8 * (r >> 2) + 4 * h8;
        *(u32*)(eL + eaddr32(hbase + 2 * row, m31))     = pack_bf2(d0[r], d1[r]);
        *(u32*)(eL + eaddr32(hbase + 2 * row + 1, m31)) = pack_bf2(e0v[r], e1v[r]);
      }
    }
    __syncthreads();   // e' visible to next stage
  }

  // ---------------- final epilogue (stage 10) ----------------
  {
    const uint4* lwq = (const uint4*)(wfrag + LW_OFF);
    uint4 lq[4][2];
    #pragma unroll
    for (int f = 0; f < 4; ++f) {
      lq[f][0] = lwq[f * 4 + h8 * 2];
      lq[f][1] = lwq[f * 4 + h8 * 2 + 1];
    }
    #pragma unroll
    for (int it = 0; it < 4; ++it) {
      int n = 128 * w + 32 * it + m31;
      float z0 = 0.f, z1 = 0.f, nr = 0.f;
      #pragma unroll
      for (int f = 0; f < 4; ++f) {
        short8 av8 = *(const short8*)(eL + eaddr(n, f * 2 + h8));
        #pragma unroll
        for (int j = 0; j < 8; ++j) {
          u32 pv = ((const u32*)&av8)[j >> 1];
          float val = __uint_as_float((j & 1) ? (pv & 0xffff0000u) : (pv << 16));
          u32 lwp = (j < 4) ? ((const u32*)&lq[f][0])[j] : ((const u32*)&lq[f][1])[j - 4];
          z0 = fmaf(val, __uint_as_float(lwp << 16), z0);
          z1 = fmaf(val, __uint_as_float(lwp & 0xffff0000u), z1);
          nr = fmaf(val, val, nr);
        }
      }
      z0 += __shfl_xor(z0, 32);
      z1 += __shfl_xor(z1, 32);
      nr += __shfl_xor(nr, 32);
      int lab = (vmask[0][n >> 5] >> (n & 31)) & 1;
      if (h8 == 0) emit_lnp(out, psta, b, n, NSTAGES - 1, z0 + lb0, z1 + lb1, nr, lab);
    }
  }
}

// Reorder preds: staging (b, s, n, 2) -> harness (b, n, s, 2). Full-line
// reads and writes via an LDS tile; one block per b, 4 n-chunks of 256.
__global__ __launch_bounds__(256) void pred_reorder_kernel(
    const float* __restrict__ psta, float* __restrict__ out) {
  __shared__ float sh[NSTAGES * 512];
  int b = blockIdx.x, tid = threadIdx.x;
  for (int chunk = 0; chunk < 4; ++chunk) {
    int n0 = chunk * 256;
    __syncthreads();
    #pragma unroll
    for (int s = 0; s < NSTAGES; ++s) {
      float2 v = *(const float2*)(psta + ((size_t)b * NSTAGES + s) * (NN * 2) +
                                  2 * (n0 + tid));
      sh[s * 512 + 2 * tid]     = v.x;
      sh[s * 512 + 2 * tid + 1] = v.y;
    }
    __syncthreads();
    size_t base = PRED_BASE + ((size_t)b * NN + n0) * (NSTAGES * 2);
    #pragma unroll
    for (int k = 0; k < 2 * NSTAGES; ++k) {
      int f = k * 256 + tid;                  // [0, 5632)
      int n_rel = (f * 2979) >> 16;           // f / 22
      int rem = f - n_rel * 22;
      out[base + f] = sh[(rem >> 1) * 512 + 2 * n_rel + (rem & 1)];
    }
  }
}

extern "C" void kernel_launch(void* const* d_in, const int* in_sizes, int n_in,
                              void* d_out, int out_size, void* d_ws, size_t ws_size,
                              hipStream_t stream) {
  const int*   x      = (const int*)d_in[0];
  const float* y      = (const float*)d_in[1];
  const float* emb_W  = (const float*)d_in[2];
  const float* emb_b  = (const float*)d_in[3];
  const float* labemb = (const float*)d_in[4];
  const float* cn_W1  = (const float*)d_in[5];
  const float* cn_b1  = (const float*)d_in[6];
  const float* cn_W2  = (const float*)d_in[7];
  const float* cn_b2  = (const float*)d_in[8];
  const float* bn_W1  = (const float*)d_in[9];
  const float* bn_b1  = (const float*)d_in[10];
  const float* bn_W2  = (const float*)d_in[11];
  const float* bn_b2  = (const float*)d_in[12];
  const float* llr_W  = (const float*)d_in[13];
  const float* llr_b  = (const float*)d_in[14];
  float* out = (float*)d_out;

  u16* wfrag = (u16*)d_ws;                         // 48*512 u16 + tables < 64 KB
  float* labW_g = (float*)((char*)d_ws + 65536);   // fp32[2][64]
  float* psta   = (float*)((char*)d_ws + (1 << 20)); // preds staging, 23 MB

  prep_kernel<<<13, 256, 0, stream>>>(cn_W1, bn_W1, cn_W2, bn_W2, labemb, llr_W,
                                      bn_b1, wfrag, labW_g);
  polar_kernel<<<NB, 512, 0, stream>>>(x, y, emb_W, emb_b, wfrag, labW_g,
                                       cn_b1, cn_b2, bn_b2, llr_W, llr_b, out, psta);
  pred_reorder_kernel<<<NB, 256, 0, stream>>>(psta, out);
}